// Round 4
// baseline (68.286 us; speedup 1.0000x reference)
//
#include <hip/hip_runtime.h>

// KnowledgeConsistentAttention v4 (MI355X / gfx950)
// sumpool3x3(scores)[p,q] = kern[p,:] . G[:,q], G = sumpool3x3(fg)
// => flash attention, K=V=kern (normalized fg cols + eps), Q = G cols, d=64.
//
// v4 vs v3: P^T LDS round-trip replaced by 8x ds_bpermute in-register
// exchange; Kt swizzle fixed to ((r>>1)&3) (even bank-quad distribution);
// exp2-domain softmax (Q prescaled by log2e in prep); vectorized prep.

typedef __bf16 bf16_t;
typedef __bf16 bf16x2 __attribute__((ext_vector_type(2)));
typedef __bf16 bf16x8 __attribute__((ext_vector_type(8)));
typedef float f32x4 __attribute__((ext_vector_type(4)));

#define HW_ 4096
#define CH 64

__device__ __forceinline__ void gload_lds16(const void* gsrc, void* lds_dst) {
  __builtin_amdgcn_global_load_lds(
      (const __attribute__((address_space(1))) unsigned int*)gsrc,
      (__attribute__((address_space(3))) unsigned int*)lds_dst, 16, 0, 0);
}

__device__ __forceinline__ int pack_bf16x2(float a, float b) {
  bf16x2 p; p[0] = (bf16_t)a; p[1] = (bf16_t)b;
  return __builtin_bit_cast(int, p);
}

// ---------------- prep: kern + pooled/prescaled Q (linear layouts) ----------------
__global__ __launch_bounds__(1024, 1) void kca_prep(const float* __restrict__ fg,
                                                    char* __restrict__ KpB,
                                                    char* __restrict__ KtB,
                                                    char* __restrict__ GtB) {
  const int b = blockIdx.x >> 6, y = blockIdx.x & 63;
  const int t = threadIdx.x;
  const float* F = fg + (size_t)b * (CH * HW_);

  __shared__ float  Ft[3 * 64 * 64];   // [r][c][x] f32, rows y-1..y+1
  __shared__ bf16_t Ks[64 * 72];       // [x][c], stride 72 (144B, 16B-aligned)
  __shared__ bf16_t Gs[64 * 72];
  __shared__ float  red[16][64];
  __shared__ float  rn[64];

  // slab: 3 float4 per thread
#pragma unroll
  for (int k = 0; k < 3; ++k) {
    const int o = t + k * 1024;          // f32x4 index
    const int r = o >> 10, c = (o >> 4) & 63, x4 = o & 15;
    const int gy = y - 1 + r;
    f32x4 v = {0.f, 0.f, 0.f, 0.f};
    if (gy >= 0 && gy <= 63) v = *(const f32x4*)(F + c * HW_ + gy * 64 + x4 * 4);
    *(f32x4*)&Ft[o * 4] = v;
  }
  __syncthreads();

  const int x = t & 63, c0 = t >> 6;     // c0 in 0..15 -> channels 4*c0..+3
  float v4[4], g4[4], ssq = 0.f;
#pragma unroll
  for (int i = 0; i < 4; ++i) {
    const int c = c0 * 4 + i;
    const float v = Ft[4096 + c * 64 + x] + 1e-7f;
    v4[i] = v; ssq = fmaf(v, v, ssq);
    float s = 0.f;
#pragma unroll
    for (int r = 0; r < 3; ++r) {
      const float* row = &Ft[r * 4096 + c * 64];
      float vv = row[x];
      if (x > 0)  vv += row[x - 1];
      if (x < 63) vv += row[x + 1];
      s += vv;
    }
    g4[i] = s * 1.4426950408889634f;     // log2e prescale (exp2-domain softmax)
  }
  red[c0][x] = ssq;
  __syncthreads();
  if (t < 512) red[t >> 6][t & 63] += red[(t >> 6) + 8][t & 63];
  __syncthreads();
  if (t < 256) red[t >> 6][t & 63] += red[(t >> 6) + 4][t & 63];
  __syncthreads();
  if (t < 64) rn[t] = 1.0f / sqrtf(red[0][t] + red[1][t] + red[2][t] + red[3][t]);
  __syncthreads();
  {
    const float rv = rn[x];
    bf16x2* ksp = (bf16x2*)((char*)Ks + x * 144 + c0 * 8);
    bf16x2* gsp = (bf16x2*)((char*)Gs + x * 144 + c0 * 8);
    bf16x2 k0; k0[0] = (bf16_t)(v4[0] * rv); k0[1] = (bf16_t)(v4[1] * rv);
    bf16x2 k1; k1[0] = (bf16_t)(v4[2] * rv); k1[1] = (bf16_t)(v4[3] * rv);
    bf16x2 g0; g0[0] = (bf16_t)g4[0]; g0[1] = (bf16_t)g4[1];
    bf16x2 g1; g1[0] = (bf16_t)g4[2]; g1[1] = (bf16_t)g4[3];
    ksp[0] = k0; ksp[1] = k1;
    gsp[0] = g0; gsp[1] = g1;
  }
  __syncthreads();

  char* Kp_b = KpB + (size_t)b * (HW_ * CH * 2) + (size_t)y * 8192;  // [p][c] 128B rows
  char* Gt_b = GtB + (size_t)b * (HW_ * CH * 2) + (size_t)y * 8192;  // [q][c] 128B rows
  char* Kt_b = KtB + (size_t)b * (CH * HW_ * 2) + (size_t)y * 128;   // [c][p] 8KB rows
  if (t < 512) {
    const int row = t >> 3, colb = (t & 7) * 16;
    *(bf16x8*)(Kp_b + row * 128 + colb) = *(const bf16x8*)((char*)Ks + row * 144 + colb);
    // Kt transpose: 8 p-elems at fixed c
    const int c = t >> 3, p0 = (t & 7) * 8;
    bf16x8 tv;
#pragma unroll
    for (int j = 0; j < 8; ++j) tv[j] = Ks[(p0 + j) * 72 + c];
    *(bf16x8*)(Kt_b + (size_t)c * 8192 + p0 * 2) = tv;
  } else {
    const int s = t - 512;
    const int row = s >> 3, colb = (s & 7) * 16;
    *(bf16x8*)(Gt_b + row * 128 + colb) = *(const bf16x8*)((char*)Gs + row * 144 + colb);
  }
}

// ---------------- main: fused flash attention, 4-way key-split ----------------
__global__ __launch_bounds__(1024, 1) void kca_attn(const char* __restrict__ KpB,
                                                    const char* __restrict__ KtB,
                                                    const char* __restrict__ GtB,
                                                    float* __restrict__ out) {
  const int b = blockIdx.x >> 6, y = blockIdx.x & 63;
  const int t = threadIdx.x;
  const int g  = t >> 8;           // key-group 0..3
  const int tl = t & 255;
  const int lane = t & 63;
  const int wv   = (t >> 6) & 3;
  const int l15  = lane & 15, lg = lane >> 4;

  const char* Kp_b = KpB + (size_t)b * (HW_ * CH * 2);
  const char* Kt_b = KtB + (size_t)b * (CH * HW_ * 2);
  const char* Gt_b = GtB + (size_t)b * (HW_ * CH * 2);
  float* Ob = out + (size_t)b * (CH * HW_);

  __shared__ __align__(16) char SM[65536];   // Kp 32K | Kt 32K (combine overlays)
  __shared__ float mlm[4][64], mll[4][64], linv[64];

  char* myKp = SM + g * 8192;            // [2][4096]: [32 p][128B swz rows]
  char* myKt = SM + 32768 + g * 8192;    // [2][4096]: [64 c][64B swz rows]

  // Q fragments in registers (wave's 16 queries; Q pre-scaled by log2e)
  const char* qrow = Gt_b + (size_t)(y * 64 + 16 * wv + l15) * 128;
  const bf16x8 qb0 = *(const bf16x8*)(qrow + 16 * lg);
  const bf16x8 qb1 = *(const bf16x8*)(qrow + 64 + 16 * lg);

  f32x4 oacc[4];
#pragma unroll
  for (int mt = 0; mt < 4; ++mt) { oacc[mt][0]=0.f; oacc[mt][1]=0.f; oacc[mt][2]=0.f; oacc[mt][3]=0.f; }
  float m_run = -INFINITY, l_run = 0.f;

  const int qr = 16 * wv + l15;
  // bpermute source lanes for the GEMM2 B-fragment exchange
  const int idxA = 4 * (l15 + 32 * (lg & 1));
  const int idxB = idxA + 64;
  const bool loLG = (lg < 2);

  const int sr1 = tl >> 3, scb1 = (tl & 7) * 16;   // Kp stage: 32 rows x 128B
  const int sr2 = tl >> 2, scb2 = (tl & 3) * 16;   // Kt stage: 64 rows x 64B

#define STAGE(D, P0)                                                                     \
  do {                                                                                   \
    gload_lds16(Kp_b + (size_t)((P0) + sr1) * 128 + (scb1 ^ ((sr1 & 7) << 4)),           \
                myKp + (D) * 4096 + tl * 16);                                            \
    gload_lds16(Kt_b + (size_t)sr2 * 8192 + (size_t)(P0) * 2 + (scb2 ^ (((sr2 >> 1) & 3) << 4)), \
                myKt + (D) * 4096 + tl * 16);                                            \
  } while (0)

  const int pbase = g * 1024;
  STAGE(0, pbase);
  int cur = 0;
  for (int it = 0; it < 32; ++it) {
    __syncthreads();                         // buf[cur] staged
    if (it + 1 < 32) STAGE(cur ^ 1, pbase + (it + 1) * 32);

    // ---- GEMM1: S[p = 16f+4lg+r][q = l15] over K=64 channels ----
    f32x4 s0, s1;
    {
      const char* kp = myKp + cur * 4096;
      int r = l15, sw = (r & 7) << 4;
      bf16x8 a0 = *(const bf16x8*)(kp + r * 128 + ((16 * lg) ^ sw));
      bf16x8 a1 = *(const bf16x8*)(kp + r * 128 + ((64 + 16 * lg) ^ sw));
      f32x4 z = {0.f, 0.f, 0.f, 0.f};
      z = __builtin_amdgcn_mfma_f32_16x16x32_bf16(a0, qb0, z, 0, 0, 0);
      z = __builtin_amdgcn_mfma_f32_16x16x32_bf16(a1, qb1, z, 0, 0, 0);
      s0 = z;
      r = 16 + l15; sw = (r & 7) << 4;
      a0 = *(const bf16x8*)(kp + r * 128 + ((16 * lg) ^ sw));
      a1 = *(const bf16x8*)(kp + r * 128 + ((64 + 16 * lg) ^ sw));
      f32x4 z1 = {0.f, 0.f, 0.f, 0.f};
      z1 = __builtin_amdgcn_mfma_f32_16x16x32_bf16(a0, qb0, z1, 0, 0, 0);
      z1 = __builtin_amdgcn_mfma_f32_16x16x32_bf16(a1, qb1, z1, 0, 0, 0);
      s1 = z1;
    }

    // ---- online softmax, exp2 domain (Q pre-scaled by log2e) ----
    float mloc = fmaxf(fmaxf(fmaxf(s0[0], s0[1]), fmaxf(s0[2], s0[3])),
                       fmaxf(fmaxf(s1[0], s1[1]), fmaxf(s1[2], s1[3])));
    mloc = fmaxf(mloc, __shfl_xor(mloc, 16));
    mloc = fmaxf(mloc, __shfl_xor(mloc, 32));
    if (!__all(mloc <= m_run)) {
      const float mnew = fmaxf(m_run, mloc);
      const float sc = exp2f(m_run - mnew);   // 0 on first tile
      m_run = mnew; l_run *= sc;
#pragma unroll
      for (int mt = 0; mt < 4; ++mt) {
        oacc[mt][0] *= sc; oacc[mt][1] *= sc; oacc[mt][2] *= sc; oacc[mt][3] *= sc;
      }
    }
    const float e00 = exp2f(s0[0] - m_run), e01 = exp2f(s0[1] - m_run);
    const float e02 = exp2f(s0[2] - m_run), e03 = exp2f(s0[3] - m_run);
    const float e10 = exp2f(s1[0] - m_run), e11 = exp2f(s1[1] - m_run);
    const float e12 = exp2f(s1[2] - m_run), e13 = exp2f(s1[3] - m_run);
    float lsum = (e00 + e01) + (e02 + e03) + (e10 + e11) + (e12 + e13);
    lsum += __shfl_xor(lsum, 16);
    lsum += __shfl_xor(lsum, 32);
    l_run += lsum;

    // ---- in-register P exchange -> GEMM2 B-fragment (8x ds_bpermute) ----
    // lane (l15,lg) needs P[p=8lg+j][q=l15]; sources: lane l15+32(lg&1) (+16),
    // words u0/u1 (lg<2) or u2/u3 (lg>=2).
    const int u0 = pack_bf16x2(e00, e01), u1 = pack_bf16x2(e02, e03);
    const int u2 = pack_bf16x2(e10, e11), u3 = pack_bf16x2(e12, e13);
    const int r0a = __builtin_amdgcn_ds_bpermute(idxA, u0);
    const int r0b = __builtin_amdgcn_ds_bpermute(idxA, u2);
    const int r1a = __builtin_amdgcn_ds_bpermute(idxA, u1);
    const int r1b = __builtin_amdgcn_ds_bpermute(idxA, u3);
    const int r2a = __builtin_amdgcn_ds_bpermute(idxB, u0);
    const int r2b = __builtin_amdgcn_ds_bpermute(idxB, u2);
    const int r3a = __builtin_amdgcn_ds_bpermute(idxB, u1);
    const int r3b = __builtin_amdgcn_ds_bpermute(idxB, u3);
    union { int w[4]; bf16x8 v; } pb;
    pb.w[0] = loLG ? r0a : r0b;
    pb.w[1] = loLG ? r1a : r1b;
    pb.w[2] = loLG ? r2a : r2b;
    pb.w[3] = loLG ? r3a : r3b;

    // ---- GEMM2: O[c = 16mt+4lg+r][q = l15] += Kt . P over K=32 p ----
    {
      const char* kt = myKt + cur * 4096;
#pragma unroll
      for (int mt = 0; mt < 4; ++mt) {
        const int r = 16 * mt + l15;
        bf16x8 a = *(const bf16x8*)(kt + r * 64 + ((16 * lg) ^ (((r >> 1) & 3) << 4)));
        oacc[mt] = __builtin_amdgcn_mfma_f32_16x16x32_bf16(a, pb.v, oacc[mt], 0, 0, 0);
      }
    }
    cur ^= 1;
  }
#undef STAGE

  // ---- combine 4 key-group partials ----
  if (lg == 0) { mlm[g][qr] = m_run; mll[g][qr] = l_run; }
  __syncthreads();                                    // C1
  const float mstar = fmaxf(fmaxf(mlm[0][qr], mlm[1][qr]), fmaxf(mlm[2][qr], mlm[3][qr]));
  const float lstar = mll[0][qr] * exp2f(mlm[0][qr] - mstar)
                    + mll[1][qr] * exp2f(mlm[1][qr] - mstar)
                    + mll[2][qr] * exp2f(mlm[2][qr] - mstar)
                    + mll[3][qr] * exp2f(mlm[3][qr] - mstar);
  const float a = exp2f(m_run - mstar);
  if (g == 0 && lg == 0) linv[qr] = 1.0f / lstar;

  float* O1 = (float*)SM;             // [64][68] f32, reuses dead Kp staging
  float* O2 = (float*)(SM + 32768);   // [64][68], reuses dead Kt staging
  if (g == 0 || g == 2) {
    float* Od = (g == 0) ? O1 : O2;
#pragma unroll
    for (int mt = 0; mt < 4; ++mt)
#pragma unroll
      for (int r = 0; r < 4; ++r)
        Od[(16 * mt + 4 * lg + r) * 68 + qr] = oacc[mt][r] * a;
  }
  __syncthreads();                                    // C2
  if (g == 1 || g == 3) {
    float* Od = (g == 1) ? O1 : O2;
#pragma unroll
    for (int mt = 0; mt < 4; ++mt)
#pragma unroll
      for (int r = 0; r < 4; ++r)
        Od[(16 * mt + 4 * lg + r) * 68 + qr] += oacc[mt][r] * a;
  }
  __syncthreads();                                    // C3
  if (t < 256) {                                      // coalesced f32x4 store
    const int c = t >> 2, qc = (t & 3) * 16;
    const float* r1 = O1 + c * 68 + qc;
    const float* r2 = O2 + c * 68 + qc;
    float* dst = Ob + (size_t)c * HW_ + y * 64 + qc;
#pragma unroll
    for (int j4 = 0; j4 < 4; ++j4) {
      f32x4 v;
#pragma unroll
      for (int j = 0; j < 4; ++j)
        v[j] = (r1[4 * j4 + j] + r2[4 * j4 + j]) * linv[qc + 4 * j4 + j];
      *(f32x4*)(dst + 4 * j4) = v;
    }
  }
}

extern "C" void kernel_launch(void* const* d_in, const int* in_sizes, int n_in,
                              void* d_out, int out_size, void* d_ws, size_t ws_size,
                              hipStream_t stream) {
  const float* fg = (const float*)d_in[0];
  float* out = (float*)d_out;
  char* ws = (char*)d_ws;
  char* Kp = ws;                 // 2 MB  [b][p][c] bf16, linear
  char* Kt = ws + (2u << 20);    // 2 MB  [b][c][p] bf16, linear
  char* Gt = ws + (4u << 20);    // 2 MB  [b][q][c] bf16, linear (pre-scaled by log2e)
  hipLaunchKernelGGL(kca_prep, dim3(256), dim3(1024), 0, stream, fg, Kp, Kt, Gt);
  hipLaunchKernelGGL(kca_attn, dim3(256), dim3(1024), 0, stream, Kp, Kt, Gt, out);
}

// Round 5
// 60.620 us; speedup vs baseline: 1.1265x; 1.1265x over previous
//
#include <hip/hip_runtime.h>

// KnowledgeConsistentAttention v5 (MI355X / gfx950)
// sumpool3x3(scores)[p,q] = kern[p,:] . G[:,q], G = sumpool3x3(fg)
// => flash attention, K=V=kern (normalized fg cols + eps), Q = G cols, d=64.
//
// v5: wave = 32 queries x 512 keys. Block 1024 thr = 8 p-groups x 2 q-strips;
// strip-waves share staged K tiles; A-fragments amortized over 2 q-subtiles.
// 16 sequential tiles of 32 keys; Kt single-buffered w/ counted vmcnt(2);
// wave-private swizzled Pt strip; 8-partial LDS combine; XCD block swizzle.

typedef __bf16 bf16_t;
typedef __bf16 bf16x2 __attribute__((ext_vector_type(2)));
typedef __bf16 bf16x8 __attribute__((ext_vector_type(8)));
typedef float f32x4 __attribute__((ext_vector_type(4)));

#define HW_ 4096
#define CH 64

static __device__ __forceinline__ void gload_lds16(const void* gsrc, void* lds_dst) {
  __builtin_amdgcn_global_load_lds(
      (const __attribute__((address_space(1))) unsigned int*)gsrc,
      (__attribute__((address_space(3))) unsigned int*)lds_dst, 16, 0, 0);
}

static __device__ __forceinline__ int pack_bf16x2(float a, float b) {
  bf16x2 p; p[0] = (bf16_t)a; p[1] = (bf16_t)b;
  return __builtin_bit_cast(int, p);
}

// ---------------- prep: kern + pooled/prescaled Q (linear layouts) ----------------
__global__ __launch_bounds__(1024, 1) void kca_prep(const float* __restrict__ fg,
                                                    char* __restrict__ KpB,
                                                    char* __restrict__ KtB,
                                                    char* __restrict__ GtB) {
  const int b = blockIdx.x >> 6, y = blockIdx.x & 63;
  const int t = threadIdx.x;
  const float* F = fg + (size_t)b * (CH * HW_);

  __shared__ float  Ft[3 * 64 * 64];   // [r][c][x] f32, rows y-1..y+1
  __shared__ bf16_t Ks[64 * 72];       // [x][c], stride 72 (144B, 16B-aligned)
  __shared__ bf16_t Gs[64 * 72];
  __shared__ float  red[16][64];
  __shared__ float  rn[64];

#pragma unroll
  for (int k = 0; k < 3; ++k) {
    const int o = t + k * 1024;          // f32x4 index
    const int r = o >> 10, c = (o >> 4) & 63, x4 = o & 15;
    const int gy = y - 1 + r;
    f32x4 v = {0.f, 0.f, 0.f, 0.f};
    if (gy >= 0 && gy <= 63) v = *(const f32x4*)(F + c * HW_ + gy * 64 + x4 * 4);
    *(f32x4*)&Ft[o * 4] = v;
  }
  __syncthreads();

  const int x = t & 63, c0 = t >> 6;     // c0 in 0..15 -> channels 4*c0..+3
  float v4[4], g4[4], ssq = 0.f;
#pragma unroll
  for (int i = 0; i < 4; ++i) {
    const int c = c0 * 4 + i;
    const float v = Ft[4096 + c * 64 + x] + 1e-7f;
    v4[i] = v; ssq = fmaf(v, v, ssq);
    float s = 0.f;
#pragma unroll
    for (int r = 0; r < 3; ++r) {
      const float* row = &Ft[r * 4096 + c * 64];
      float vv = row[x];
      if (x > 0)  vv += row[x - 1];
      if (x < 63) vv += row[x + 1];
      s += vv;
    }
    g4[i] = s * 1.4426950408889634f;     // log2e prescale (exp2-domain softmax)
  }
  red[c0][x] = ssq;
  __syncthreads();
  if (t < 512) red[t >> 6][t & 63] += red[(t >> 6) + 8][t & 63];
  __syncthreads();
  if (t < 256) red[t >> 6][t & 63] += red[(t >> 6) + 4][t & 63];
  __syncthreads();
  if (t < 64) rn[t] = 1.0f / sqrtf(red[0][t] + red[1][t] + red[2][t] + red[3][t]);
  __syncthreads();
  {
    const float rv = rn[x];
    bf16x2* ksp = (bf16x2*)((char*)Ks + x * 144 + c0 * 8);
    bf16x2* gsp = (bf16x2*)((char*)Gs + x * 144 + c0 * 8);
    bf16x2 k0; k0[0] = (bf16_t)(v4[0] * rv); k0[1] = (bf16_t)(v4[1] * rv);
    bf16x2 k1; k1[0] = (bf16_t)(v4[2] * rv); k1[1] = (bf16_t)(v4[3] * rv);
    bf16x2 g0; g0[0] = (bf16_t)g4[0]; g0[1] = (bf16_t)g4[1];
    bf16x2 g1; g1[0] = (bf16_t)g4[2]; g1[1] = (bf16_t)g4[3];
    ksp[0] = k0; ksp[1] = k1;
    gsp[0] = g0; gsp[1] = g1;
  }
  __syncthreads();

  char* Kp_b = KpB + (size_t)b * (HW_ * CH * 2) + (size_t)y * 8192;  // [p][c] 128B rows
  char* Gt_b = GtB + (size_t)b * (HW_ * CH * 2) + (size_t)y * 8192;  // [q][c] 128B rows
  char* Kt_b = KtB + (size_t)b * (CH * HW_ * 2) + (size_t)y * 128;   // [c][p] 8KB rows
  if (t < 512) {
    const int row = t >> 3, colb = (t & 7) * 16;
    *(bf16x8*)(Kp_b + row * 128 + colb) = *(const bf16x8*)((char*)Ks + row * 144 + colb);
    const int c = t >> 3, p0 = (t & 7) * 8;
    bf16x8 tv;
#pragma unroll
    for (int j = 0; j < 8; ++j) tv[j] = Ks[(p0 + j) * 72 + c];
    *(bf16x8*)(Kt_b + (size_t)c * 8192 + p0 * 2) = tv;
  } else {
    const int s = t - 512;
    const int row = s >> 3, colb = (s & 7) * 16;
    *(bf16x8*)(Gt_b + row * 128 + colb) = *(const bf16x8*)((char*)Gs + row * 144 + colb);
  }
}

// ---------------- main: fused flash attention ----------------
__global__ __launch_bounds__(1024, 4) void kca_attn(const char* __restrict__ KpB,
                                                    const char* __restrict__ KtB,
                                                    const char* __restrict__ GtB,
                                                    float* __restrict__ out) {
  // XCD-aware remap: give each XCD (blk % 8) a contiguous half-batch (2MB, L2-fit)
  const int sw_id = ((blockIdx.x & 7) << 5) | (blockIdx.x >> 3);
  const int b = sw_id >> 6, y = sw_id & 63;
  const int t = threadIdx.x;
  const int lane = t & 63, w = t >> 6;
  const int g = w & 7;           // p-group 0..7
  const int st = w >> 3;         // q-strip 0..1 (q offset st*32)
  const int l15 = lane & 15, lg = lane >> 4;

  const char* Kp_b = KpB + (size_t)b * (HW_ * CH * 2);
  const char* Kt_b = KtB + (size_t)b * (CH * HW_ * 2);
  const char* Gt_b = GtB + (size_t)b * (HW_ * CH * 2);
  float* Ob = out + (size_t)b * (CH * HW_);

  __shared__ __align__(16) char SM[98304];     // Kp 8g x 2buf x 4K | Kt 8g x 4K; combine overlay
  __shared__ __align__(16) char PtB[32768];    // 16 waves x 2K (16 rows x 128B swz)
  __shared__ float mlm[8][64], mll[8][64], linv[64];

  char* KpG = SM + g * 8192;
  char* KtG = SM + 65536 + g * 4096;
  char* Ptw = PtB + w * 2048;

  // Q fragments: wave's 32 queries (2 subtiles of 16), Q pre-scaled by log2e
  bf16x8 qb00, qb01, qb10, qb11;
  {
    const char* qr0 = Gt_b + (size_t)(y * 64 + st * 32 + l15) * 128;
    const char* qr1 = qr0 + 16 * 128;
    qb00 = *(const bf16x8*)(qr0 + 16 * lg);
    qb01 = *(const bf16x8*)(qr0 + 64 + 16 * lg);
    qb10 = *(const bf16x8*)(qr1 + 16 * lg);
    qb11 = *(const bf16x8*)(qr1 + 64 + 16 * lg);
  }

  // staging lane constants (group tile = 256 chunks of 16B; 2 waves x 2 chunks)
  const int cA = st * 128 + lane, cB = cA + 64;
  const int rA1 = cA >> 3, rB1 = cB >> 3;      // Kp rows
  const int rA2 = cA >> 2, rB2 = cB >> 2;      // Kt rows
  const size_t kpoffA = (size_t)rA1 * 128 + (((cA & 7) * 16) ^ ((rA1 & 7) << 4));
  const size_t kpoffB = (size_t)rB1 * 128 + (((cB & 7) * 16) ^ ((rB1 & 7) << 4));
  const size_t ktoffA = (size_t)rA2 * 8192 + (((cA & 3) * 16) ^ (((rA2 >> 1) & 3) << 4));
  const size_t ktoffB = (size_t)rB2 * 8192 + (((cB & 3) * 16) ^ (((rB2 >> 1) & 3) << 4));

#define STAGE_KP(D, P0)                                                        \
  do {                                                                         \
    gload_lds16(Kp_b + (size_t)(P0) * 128 + kpoffA, KpG + (D) * 4096 + cA * 16); \
    gload_lds16(Kp_b + (size_t)(P0) * 128 + kpoffB, KpG + (D) * 4096 + cB * 16); \
  } while (0)
#define STAGE_KT(P0)                                                           \
  do {                                                                         \
    gload_lds16(Kt_b + (size_t)(P0) * 2 + ktoffA, KtG + cA * 16);              \
    gload_lds16(Kt_b + (size_t)(P0) * 2 + ktoffB, KtG + cB * 16);              \
  } while (0)

  f32x4 oacc[2][4];
#pragma unroll
  for (int s = 0; s < 2; ++s)
#pragma unroll
    for (int mt = 0; mt < 4; ++mt) { oacc[s][mt][0]=0.f; oacc[s][mt][1]=0.f; oacc[s][mt][2]=0.f; oacc[s][mt][3]=0.f; }
  float m_s[2] = {-INFINITY, -INFINITY}, l_s[2] = {0.f, 0.f};

  const int pb0 = g * 512;
  char* ptrow = Ptw + l15 * 128;
  const int psw = (l15 & 7) << 4;

  STAGE_KP(0, pb0);
  int cur = 0;
  for (int it = 0; it < 16; ++it) {
    __syncthreads();                       // Kp[cur] staged; Kt region free
    STAGE_KT(pb0 + it * 32);               // issue order: 2x KT then 2x KP
    STAGE_KP(cur ^ 1, pb0 + ((it + 1) & 15) * 32);

    // ---- GEMM1: S[s][p = f*16+4lg+r][q = s*16+l15], K=64 channels ----
    const char* kp = KpG + cur * 4096;
    f32x4 S[2][2];
#pragma unroll
    for (int f = 0; f < 2; ++f) {
      const int r = f * 16 + l15, swr = (r & 7) << 4;
      bf16x8 a0 = *(const bf16x8*)(kp + r * 128 + ((16 * lg) ^ swr));
      bf16x8 a1 = *(const bf16x8*)(kp + r * 128 + ((64 + 16 * lg) ^ swr));
      f32x4 z0 = {0.f, 0.f, 0.f, 0.f};
      z0 = __builtin_amdgcn_mfma_f32_16x16x32_bf16(a0, qb00, z0, 0, 0, 0);
      z0 = __builtin_amdgcn_mfma_f32_16x16x32_bf16(a1, qb01, z0, 0, 0, 0);
      S[0][f] = z0;
      f32x4 z1 = {0.f, 0.f, 0.f, 0.f};
      z1 = __builtin_amdgcn_mfma_f32_16x16x32_bf16(a0, qb10, z1, 0, 0, 0);
      z1 = __builtin_amdgcn_mfma_f32_16x16x32_bf16(a1, qb11, z1, 0, 0, 0);
      S[1][f] = z1;
    }

    // ---- online softmax per q-subtile (exp2 domain) ----
#pragma unroll
    for (int s = 0; s < 2; ++s) {
      float mloc = fmaxf(fmaxf(fmaxf(S[s][0][0], S[s][0][1]), fmaxf(S[s][0][2], S[s][0][3])),
                         fmaxf(fmaxf(S[s][1][0], S[s][1][1]), fmaxf(S[s][1][2], S[s][1][3])));
      mloc = fmaxf(mloc, __shfl_xor(mloc, 16));
      mloc = fmaxf(mloc, __shfl_xor(mloc, 32));
      if (!__all(mloc <= m_s[s])) {        // exact skip-rescale
        const float mnew = fmaxf(m_s[s], mloc);
        const float sc = exp2f(m_s[s] - mnew);   // 0 on first tile
        m_s[s] = mnew; l_s[s] *= sc;
#pragma unroll
        for (int mt = 0; mt < 4; ++mt) {
          oacc[s][mt][0] *= sc; oacc[s][mt][1] *= sc;
          oacc[s][mt][2] *= sc; oacc[s][mt][3] *= sc;
        }
      }
      float lsum = 0.f;
#pragma unroll
      for (int f = 0; f < 2; ++f) {
#pragma unroll
        for (int rp = 0; rp < 2; ++rp) {
          const float e0 = exp2f(S[s][f][2 * rp]     - m_s[s]);
          const float e1 = exp2f(S[s][f][2 * rp + 1] - m_s[s]);
          lsum += e0 + e1;
          *(int*)(ptrow + ((s * 64 + f * 32 + lg * 8 + rp * 4) ^ psw)) = pack_bf16x2(e0, e1);
        }
      }
      lsum += __shfl_xor(lsum, 16);
      lsum += __shfl_xor(lsum, 32);
      l_s[s] += lsum;
    }

    // wait only the 2 KT loads (leave the 2 KP prefetch loads in flight)
    asm volatile("s_waitcnt vmcnt(2)" ::: "memory");

    // ---- GEMM2: O[s][c = 16mt+4lg+r][q = s*16+l15] += Kt . P, K=32 p ----
    bf16x8 pbf0 = *(const bf16x8*)(ptrow + ((16 * lg) ^ psw));
    bf16x8 pbf1 = *(const bf16x8*)(ptrow + ((64 + 16 * lg) ^ psw));
#pragma unroll
    for (int mt = 0; mt < 4; ++mt) {
      const int r = 16 * mt + l15;
      bf16x8 a = *(const bf16x8*)(KtG + r * 64 + ((16 * lg) ^ (((r >> 1) & 3) << 4)));
      oacc[0][mt] = __builtin_amdgcn_mfma_f32_16x16x32_bf16(a, pbf0, oacc[0][mt], 0, 0, 0);
      oacc[1][mt] = __builtin_amdgcn_mfma_f32_16x16x32_bf16(a, pbf1, oacc[1][mt], 0, 0, 0);
    }
    cur ^= 1;
  }
#undef STAGE_KP
#undef STAGE_KT

  // ---- combine 8 p-group partials ----
  if (lg == 0) {
#pragma unroll
    for (int s = 0; s < 2; ++s) {
      mlm[g][st * 32 + s * 16 + l15] = m_s[s];
      mll[g][st * 32 + s * 16 + l15] = l_s[s];
    }
  }
  __syncthreads();                                   // C1: all compute + staging done
  float alpha[2];
#pragma unroll
  for (int s = 0; s < 2; ++s) {
    const int q = st * 32 + s * 16 + l15;
    float mstar = mlm[0][q];
#pragma unroll
    for (int k = 1; k < 8; ++k) mstar = fmaxf(mstar, mlm[k][q]);
    float lst = 0.f;
#pragma unroll
    for (int k = 0; k < 8; ++k) lst += mll[k][q] * exp2f(mlm[k][q] - mstar);
    alpha[s] = exp2f(m_s[s] - mstar);
    if (g == 0 && lg == 0) linv[q] = 1.0f / lst;
  }
  // 4 regions [64c][72 f32] overlaid on dead staging LDS; even g writes, odd adds
  float* Rg = (float*)SM + (g >> 1) * 4608;
  if ((g & 1) == 0) {
#pragma unroll
    for (int s = 0; s < 2; ++s)
#pragma unroll
      for (int mt = 0; mt < 4; ++mt)
#pragma unroll
        for (int r = 0; r < 4; ++r)
          Rg[(16 * mt + 4 * lg + r) * 72 + st * 32 + s * 16 + l15] = oacc[s][mt][r] * alpha[s];
  }
  __syncthreads();                                   // C2
  if (g & 1) {
#pragma unroll
    for (int s = 0; s < 2; ++s)
#pragma unroll
      for (int mt = 0; mt < 4; ++mt)
#pragma unroll
        for (int r = 0; r < 4; ++r)
          Rg[(16 * mt + 4 * lg + r) * 72 + st * 32 + s * 16 + l15] += oacc[s][mt][r] * alpha[s];
  }
  __syncthreads();                                   // C3
  {
    const int c = t >> 4, q4 = (t & 15) * 4;
    const float* R0 = (const float*)SM;
    f32x4 v = *(const f32x4*)(R0 + c * 72 + q4);
    v += *(const f32x4*)(R0 + 4608 + c * 72 + q4);
    v += *(const f32x4*)(R0 + 9216 + c * 72 + q4);
    v += *(const f32x4*)(R0 + 13824 + c * 72 + q4);
    const f32x4 li = *(const f32x4*)(linv + q4);
    f32x4 o;
#pragma unroll
    for (int j = 0; j < 4; ++j) o[j] = v[j] * li[j];
    *(f32x4*)(Ob + (size_t)c * HW_ + y * 64 + q4) = o;
  }
}

extern "C" void kernel_launch(void* const* d_in, const int* in_sizes, int n_in,
                              void* d_out, int out_size, void* d_ws, size_t ws_size,
                              hipStream_t stream) {
  const float* fg = (const float*)d_in[0];
  float* out = (float*)d_out;
  char* ws = (char*)d_ws;
  char* Kp = ws;                 // 2 MB  [b][p][c] bf16, linear
  char* Kt = ws + (2u << 20);    // 2 MB  [b][c][p] bf16, linear
  char* Gt = ws + (4u << 20);    // 2 MB  [b][q][c] bf16, linear (pre-scaled by log2e)
  hipLaunchKernelGGL(kca_prep, dim3(256), dim3(1024), 0, stream, fg, Kp, Kt, Gt);
  hipLaunchKernelGGL(kca_attn, dim3(256), dim3(1024), 0, stream, Kp, Kt, Gt, out);
}

// Round 6
// 44.029 us; speedup vs baseline: 1.5509x; 1.3768x over previous
//
#include <hip/hip_runtime.h>

// KnowledgeConsistentAttention v6 (MI355X / gfx950)
// sumpool3x3(scores)[p,q] = kern[p,:] . G[:,q], G = sumpool3x3(fg)
// => flash attention, K=V=kern (normalized fg cols + eps), Q = G cols, d=64.
//
// v6: fixed-bias softmax (exp2 with no max tracking -- |S.log2e| <= ~45,
// f32/bf16 ranges cover it) and operand-swapped GEMM2 (O^T = mfma(P, kern)):
// GEMM1's output IS the GEMM2 A-fragment after exp2+pack (no lane exchange),
// kern's B-fragments are pre-permuted in ws (KB) and read direct from global.
// DS ops per wave-iter: 4 A-frag reads + Kp stage. No Pt, no Kt, no shfl.

typedef __bf16 bf16_t;
typedef __bf16 bf16x2 __attribute__((ext_vector_type(2)));
typedef __bf16 bf16x8 __attribute__((ext_vector_type(8)));
typedef float f32x4 __attribute__((ext_vector_type(4)));

#define HW_ 4096
#define CH 64

static __device__ __forceinline__ void gload_lds16(const void* gsrc, void* lds_dst) {
  __builtin_amdgcn_global_load_lds(
      (const __attribute__((address_space(1))) unsigned int*)gsrc,
      (__attribute__((address_space(3))) unsigned int*)lds_dst, 16, 0, 0);
}

static __device__ __forceinline__ int pack_bf16x2(float a, float b) {
  bf16x2 p; p[0] = (bf16_t)a; p[1] = (bf16_t)b;
  return __builtin_bit_cast(int, p);
}

// ---------------- prep: kern (2 layouts) + pooled/prescaled Q ----------------
__global__ __launch_bounds__(1024, 1) void kca_prep(const float* __restrict__ fg,
                                                    char* __restrict__ KpB,
                                                    char* __restrict__ KBB,
                                                    char* __restrict__ GtB) {
  const int b = blockIdx.x >> 6, y = blockIdx.x & 63;
  const int t = threadIdx.x;
  const float* F = fg + (size_t)b * (CH * HW_);

  __shared__ float  Ft[3 * 64 * 64];   // [r][c][x] f32, rows y-1..y+1
  __shared__ bf16_t Ks[64 * 72];       // [x][c], stride 72 (144B, 16B-aligned)
  __shared__ bf16_t Gs[64 * 72];
  __shared__ float  red[16][64];
  __shared__ float  rn[64];

#pragma unroll
  for (int k = 0; k < 3; ++k) {
    const int o = t + k * 1024;          // f32x4 index
    const int r = o >> 10, c = (o >> 4) & 63, x4 = o & 15;
    const int gy = y - 1 + r;
    f32x4 v = {0.f, 0.f, 0.f, 0.f};
    if (gy >= 0 && gy <= 63) v = *(const f32x4*)(F + c * HW_ + gy * 64 + x4 * 4);
    *(f32x4*)&Ft[o * 4] = v;
  }
  __syncthreads();

  const int x = t & 63, c0 = t >> 6;     // c0 in 0..15 -> channels 4*c0..+3
  float v4[4], g4[4], ssq = 0.f;
#pragma unroll
  for (int i = 0; i < 4; ++i) {
    const int c = c0 * 4 + i;
    const float v = Ft[4096 + c * 64 + x] + 1e-7f;
    v4[i] = v; ssq = fmaf(v, v, ssq);
    float s = 0.f;
#pragma unroll
    for (int r = 0; r < 3; ++r) {
      const float* row = &Ft[r * 4096 + c * 64];
      float vv = row[x];
      if (x > 0)  vv += row[x - 1];
      if (x < 63) vv += row[x + 1];
      s += vv;
    }
    g4[i] = s * 1.4426950408889634f;     // log2e prescale (exp2-domain softmax)
  }
  red[c0][x] = ssq;
  __syncthreads();
  if (t < 512) red[t >> 6][t & 63] += red[(t >> 6) + 8][t & 63];
  __syncthreads();
  if (t < 256) red[t >> 6][t & 63] += red[(t >> 6) + 4][t & 63];
  __syncthreads();
  if (t < 64) rn[t] = 1.0f / sqrtf(red[0][t] + red[1][t] + red[2][t] + red[3][t]);
  __syncthreads();
  {
    const float rv = rn[x];
    bf16x2* ksp = (bf16x2*)((char*)Ks + x * 144 + c0 * 8);
    bf16x2* gsp = (bf16x2*)((char*)Gs + x * 144 + c0 * 8);
    bf16x2 k0; k0[0] = (bf16_t)(v4[0] * rv); k0[1] = (bf16_t)(v4[1] * rv);
    bf16x2 k1; k1[0] = (bf16_t)(v4[2] * rv); k1[1] = (bf16_t)(v4[3] * rv);
    bf16x2 g0; g0[0] = (bf16_t)g4[0]; g0[1] = (bf16_t)g4[1];
    bf16x2 g1; g1[0] = (bf16_t)g4[2]; g1[1] = (bf16_t)g4[3];
    ksp[0] = k0; ksp[1] = k1;
    gsp[0] = g0; gsp[1] = g1;
  }
  __syncthreads();

  char* Kp_b = KpB + (size_t)b * (HW_ * CH * 2) + (size_t)y * 8192;  // [p][c] 128B rows
  char* Gt_b = GtB + (size_t)b * (HW_ * CH * 2) + (size_t)y * 8192;  // [q][c] 128B rows
  char* KB_b = KBB + (size_t)b * (HW_ * CH * 2);                     // [tile][mt][lane][16B]
  if (t < 512) {
    const int row = t >> 3, colb = (t & 7) * 16;
    *(bf16x8*)(Kp_b + row * 128 + colb) = *(const bf16x8*)((char*)Ks + row * 144 + colb);
    // KB: GEMM2 B-fragment order with slot permutation baked in.
    // lane(l15,lg) word j = kern[tile*32 + 16*(j>>2) + 4*lg + (j&3)][16*mt + l15]
    const int tile = t >> 8;           // 0..1
    const int mt   = (t >> 6) & 3;
    const int ln   = t & 63;
    const int l15_ = ln & 15, lg_ = ln >> 4;
    bf16x8 kv;
#pragma unroll
    for (int j = 0; j < 8; ++j) {
      const int pl = tile * 32 + 16 * (j >> 2) + 4 * lg_ + (j & 3);
      kv[j] = Ks[pl * 72 + 16 * mt + l15_];
    }
    *(bf16x8*)(KB_b + (size_t)(2 * y + tile) * 4096 + mt * 1024 + ln * 16) = kv;
  } else {
    const int s = t - 512;
    const int row = s >> 3, colb = (s & 7) * 16;
    *(bf16x8*)(Gt_b + row * 128 + colb) = *(const bf16x8*)((char*)Gs + row * 144 + colb);
  }
}

// ---------------- main: fused flash attention ----------------
__global__ __launch_bounds__(1024, 4) void kca_attn(const char* __restrict__ KpB,
                                                    const char* __restrict__ KBB,
                                                    const char* __restrict__ GtB,
                                                    float* __restrict__ out) {
  // XCD-aware remap: each XCD gets a contiguous half-batch (L2-fit)
  const int sw_id = ((blockIdx.x & 7) << 5) | (blockIdx.x >> 3);
  const int b = sw_id >> 6, y = sw_id & 63;
  const int t = threadIdx.x;
  const int lane = t & 63, w = t >> 6;
  const int g = w & 7;           // p-group 0..7 (keys g*512 .. +512)
  const int st = w >> 3;         // q-strip 0..1 (q offset st*32)
  const int l15 = lane & 15, lg = lane >> 4;

  const char* Kp_b = KpB + (size_t)b * (HW_ * CH * 2);
  const char* KB_b = KBB + (size_t)b * (HW_ * CH * 2);
  const char* Gt_b = GtB + (size_t)b * (HW_ * CH * 2);
  float* Ob = out + (size_t)b * (CH * HW_);

  __shared__ __align__(16) char SM[69632];   // loop: Kp 8g x 2buf x 4K; combine: 4 x [64][68] f32
  __shared__ float mll[8][64];
  __shared__ float linv[64];

  char* KpG = SM + g * 8192;

  // Q fragments (wave's 32 queries, pre-scaled by log2e)
  bf16x8 qb00, qb01, qb10, qb11;
  {
    const char* qr0 = Gt_b + (size_t)(y * 64 + st * 32 + l15) * 128;
    const char* qr1 = qr0 + 16 * 128;
    qb00 = *(const bf16x8*)(qr0 + 16 * lg);
    qb01 = *(const bf16x8*)(qr0 + 64 + 16 * lg);
    qb10 = *(const bf16x8*)(qr1 + 16 * lg);
    qb11 = *(const bf16x8*)(qr1 + 64 + 16 * lg);
  }

  // staging constants (group Kp tile = 256 x 16B chunks, 2 waves x 2 chunks)
  const int cA = st * 128 + lane, cB = cA + 64;
  const int rA1 = cA >> 3, rB1 = cB >> 3;
  const size_t kpoffA = (size_t)rA1 * 128 + (((cA & 7) * 16) ^ ((rA1 & 7) << 4));
  const size_t kpoffB = (size_t)rB1 * 128 + (((cB & 7) * 16) ^ ((rB1 & 7) << 4));

#define STAGE_KP(D, P0)                                                          \
  do {                                                                           \
    gload_lds16(Kp_b + (size_t)(P0) * 128 + kpoffA, KpG + (D) * 4096 + cA * 16); \
    gload_lds16(Kp_b + (size_t)(P0) * 128 + kpoffB, KpG + (D) * 4096 + cB * 16); \
  } while (0)

  f32x4 oaccT[2][4];
#pragma unroll
  for (int s = 0; s < 2; ++s)
#pragma unroll
    for (int mt = 0; mt < 4; ++mt) { oaccT[s][mt][0]=0.f; oaccT[s][mt][1]=0.f; oaccT[s][mt][2]=0.f; oaccT[s][mt][3]=0.f; }
  float lpart0 = 0.f, lpart1 = 0.f;

  const int pb0 = g * 512;
  STAGE_KP(0, pb0);
  int cur = 0;
  for (int it = 0; it < 16; ++it) {
    __syncthreads();                       // Kp[cur] staged
    // B-fragments for this tile: 4 coalesced 1KB wave-loads, L1/L2-resident;
    // latency hides under GEMM1 + exp (compiler-inserted vmcnt before GEMM2).
    const char* kbp = KB_b + (size_t)(g * 16 + it) * 4096 + lane * 16;
    const bf16x8 kb0 = *(const bf16x8*)(kbp);
    const bf16x8 kb1 = *(const bf16x8*)(kbp + 1024);
    const bf16x8 kb2 = *(const bf16x8*)(kbp + 2048);
    const bf16x8 kb3 = *(const bf16x8*)(kbp + 3072);
    if (it + 1 < 16) STAGE_KP(cur ^ 1, pb0 + (it + 1) * 32);

    // ---- GEMM1: S[s][p = f*16+4lg+r][q = st*32+s*16+l15], K=64 channels ----
    const char* kp = KpG + cur * 4096;
    f32x4 S[2][2];
#pragma unroll
    for (int f = 0; f < 2; ++f) {
      const int r = f * 16 + l15, swr = (r & 7) << 4;
      bf16x8 a0 = *(const bf16x8*)(kp + r * 128 + ((16 * lg) ^ swr));
      bf16x8 a1 = *(const bf16x8*)(kp + r * 128 + ((64 + 16 * lg) ^ swr));
      f32x4 z0 = {0.f, 0.f, 0.f, 0.f};
      z0 = __builtin_amdgcn_mfma_f32_16x16x32_bf16(a0, qb00, z0, 0, 0, 0);
      z0 = __builtin_amdgcn_mfma_f32_16x16x32_bf16(a1, qb01, z0, 0, 0, 0);
      S[0][f] = z0;
      f32x4 z1 = {0.f, 0.f, 0.f, 0.f};
      z1 = __builtin_amdgcn_mfma_f32_16x16x32_bf16(a0, qb10, z1, 0, 0, 0);
      z1 = __builtin_amdgcn_mfma_f32_16x16x32_bf16(a1, qb11, z1, 0, 0, 0);
      S[1][f] = z1;
    }

    // ---- fixed-bias softmax numerators: P = exp2(S) (no max needed) ----
    // pack in k-slot order j=0..7 -> GEMM2 A-fragment, no lane exchange.
    union { int wd[4]; bf16x8 v; } pa0, pa1;
    {
      const float e0 = exp2f(S[0][0][0]), e1 = exp2f(S[0][0][1]);
      const float e2 = exp2f(S[0][0][2]), e3 = exp2f(S[0][0][3]);
      const float e4 = exp2f(S[0][1][0]), e5 = exp2f(S[0][1][1]);
      const float e6 = exp2f(S[0][1][2]), e7 = exp2f(S[0][1][3]);
      lpart0 += ((e0 + e1) + (e2 + e3)) + ((e4 + e5) + (e6 + e7));
      pa0.wd[0] = pack_bf16x2(e0, e1); pa0.wd[1] = pack_bf16x2(e2, e3);
      pa0.wd[2] = pack_bf16x2(e4, e5); pa0.wd[3] = pack_bf16x2(e6, e7);
    }
    {
      const float e0 = exp2f(S[1][0][0]), e1 = exp2f(S[1][0][1]);
      const float e2 = exp2f(S[1][0][2]), e3 = exp2f(S[1][0][3]);
      const float e4 = exp2f(S[1][1][0]), e5 = exp2f(S[1][1][1]);
      const float e6 = exp2f(S[1][1][2]), e7 = exp2f(S[1][1][3]);
      lpart1 += ((e0 + e1) + (e2 + e3)) + ((e4 + e5) + (e6 + e7));
      pa1.wd[0] = pack_bf16x2(e0, e1); pa1.wd[1] = pack_bf16x2(e2, e3);
      pa1.wd[2] = pack_bf16x2(e4, e5); pa1.wd[3] = pack_bf16x2(e6, e7);
    }

    // ---- GEMM2 (swapped): O^T[q = 4lg+r][c = 16mt+l15] += P . kern ----
    oaccT[0][0] = __builtin_amdgcn_mfma_f32_16x16x32_bf16(pa0.v, kb0, oaccT[0][0], 0, 0, 0);
    oaccT[1][0] = __builtin_amdgcn_mfma_f32_16x16x32_bf16(pa1.v, kb0, oaccT[1][0], 0, 0, 0);
    oaccT[0][1] = __builtin_amdgcn_mfma_f32_16x16x32_bf16(pa0.v, kb1, oaccT[0][1], 0, 0, 0);
    oaccT[1][1] = __builtin_amdgcn_mfma_f32_16x16x32_bf16(pa1.v, kb1, oaccT[1][1], 0, 0, 0);
    oaccT[0][2] = __builtin_amdgcn_mfma_f32_16x16x32_bf16(pa0.v, kb2, oaccT[0][2], 0, 0, 0);
    oaccT[1][2] = __builtin_amdgcn_mfma_f32_16x16x32_bf16(pa1.v, kb2, oaccT[1][2], 0, 0, 0);
    oaccT[0][3] = __builtin_amdgcn_mfma_f32_16x16x32_bf16(pa0.v, kb3, oaccT[0][3], 0, 0, 0);
    oaccT[1][3] = __builtin_amdgcn_mfma_f32_16x16x32_bf16(pa1.v, kb3, oaccT[1][3], 0, 0, 0);
    cur ^= 1;
  }
#undef STAGE_KP

  // ---- reduce l partials over the 4 lane-groups, publish per p-group ----
  lpart0 += __shfl_xor(lpart0, 16); lpart0 += __shfl_xor(lpart0, 32);
  lpart1 += __shfl_xor(lpart1, 16); lpart1 += __shfl_xor(lpart1, 32);
  if (lg == 0) {
    mll[g][st * 32 + l15]      = lpart0;
    mll[g][st * 32 + 16 + l15] = lpart1;
  }
  __syncthreads();                                   // C1: loop LDS dead
  if (t < 64) {
    float L = 0.f;
#pragma unroll
    for (int k = 0; k < 8; ++k) L += mll[k][t];
    linv[t] = 1.0f / L;
  }
  // combine O^T partials: 4 regions [c=64][q stride 68] f32, shared bias => plain sums
  float* Rg = (float*)SM + (g >> 1) * 4352;
  if ((g & 1) == 0) {
#pragma unroll
    for (int s = 0; s < 2; ++s)
#pragma unroll
      for (int mt = 0; mt < 4; ++mt)
#pragma unroll
        for (int r = 0; r < 4; ++r)
          Rg[(16 * mt + l15) * 68 + st * 32 + s * 16 + 4 * lg + r] = oaccT[s][mt][r];
  }
  __syncthreads();                                   // C2
  if (g & 1) {
#pragma unroll
    for (int s = 0; s < 2; ++s)
#pragma unroll
      for (int mt = 0; mt < 4; ++mt)
#pragma unroll
        for (int r = 0; r < 4; ++r)
          Rg[(16 * mt + l15) * 68 + st * 32 + s * 16 + 4 * lg + r] += oaccT[s][mt][r];
  }
  __syncthreads();                                   // C3
  {
    const int c = t >> 4, q4 = (t & 15) * 4;
    const float* R0 = (const float*)SM;
    f32x4 v = *(const f32x4*)(R0 + c * 68 + q4);
    v += *(const f32x4*)(R0 + 4352 + c * 68 + q4);
    v += *(const f32x4*)(R0 + 8704 + c * 68 + q4);
    v += *(const f32x4*)(R0 + 13056 + c * 68 + q4);
    const f32x4 li = *(const f32x4*)(linv + q4);
    f32x4 o;
#pragma unroll
    for (int j = 0; j < 4; ++j) o[j] = v[j] * li[j];
    *(f32x4*)(Ob + (size_t)c * HW_ + y * 64 + q4) = o;
  }
}

extern "C" void kernel_launch(void* const* d_in, const int* in_sizes, int n_in,
                              void* d_out, int out_size, void* d_ws, size_t ws_size,
                              hipStream_t stream) {
  const float* fg = (const float*)d_in[0];
  float* out = (float*)d_out;
  char* ws = (char*)d_ws;
  char* Kp = ws;                 // 2 MB  [b][p][c] bf16, linear (A-side kern)
  char* KB = ws + (2u << 20);    // 2 MB  [b][tile][mt][lane][16B] (B-side kern, permuted)
  char* Gt = ws + (4u << 20);    // 2 MB  [b][q][c] bf16 (pooled Q, log2e-prescaled)
  hipLaunchKernelGGL(kca_prep, dim3(256), dim3(1024), 0, stream, fg, Kp, KB, Gt);
  hipLaunchKernelGGL(kca_attn, dim3(256), dim3(1024), 0, stream, Kp, KB, Gt, out);
}